// Round 3
// baseline (282.119 us; speedup 1.0000x reference)
//
#include <hip/hip_runtime.h>
#include <math.h>

#define F_EPS 1e-15f
#define F_BALL_EPS 1e-5f
#define F_TANH_ARG_MAX 15.0f
#define F_ATANH_MAX (1.0f - 1e-7f)
#define F_LOG2E 1.4426950408889634f
#define F_LN2   0.6931471805599453f

// ---- fast hardware math (v_rcp/v_sqrt/v_exp/v_log are single instrs) ----
__device__ __forceinline__ float rcp_fast(float x) {
    float r = __builtin_amdgcn_rcpf(x);
    return r * (2.0f - x * r);                  // 1 Newton step -> ~fp32 accurate
}
__device__ __forceinline__ float div_fast(float a, float b) { return a * rcp_fast(b); }
__device__ __forceinline__ float sqrt_fast(float x) { return __builtin_amdgcn_sqrtf(x); }
__device__ __forceinline__ float exp2_fast(float x) { return __builtin_amdgcn_exp2f(x); }
__device__ __forceinline__ float log2_fast(float x) { return __builtin_amdgcn_logf(x); }
__device__ __forceinline__ float exp_fast(float x)  { return exp2_fast(x * F_LOG2E); }

__device__ __forceinline__ float tanh_fast(float x) {
    float ax = fabsf(x);
    float t  = exp2_fast(ax * (-2.0f * F_LOG2E));     // e^{-2|x|}
    float r  = (1.0f - t) * rcp_fast(1.0f + t);
    return copysignf(r, x);
}
__device__ __forceinline__ float atanh_fast(float z) {   // z in [0, 1)
    return (0.5f * F_LN2) * log2_fast((1.0f + z) * rcp_fast(1.0f - z));
}
__device__ __forceinline__ float softplus_fast(float x) {
    return F_LN2 * log2_fast(1.0f + exp2_fast(x * F_LOG2E));
}

struct Gram { float X2, Y2, XY; };

__device__ __forceinline__ float g_norm2(const Gram& g, float a, float b) {
    return fmaxf(a * a * g.X2 + 2.0f * a * b * g.XY + b * b * g.Y2, 0.0f);
}
__device__ __forceinline__ float g_norm(const Gram& g, float a, float b) {
    return fmaxf(sqrt_fast(g_norm2(g, a, b)), F_EPS);
}
__device__ __forceinline__ float g_dot(const Gram& g, float au, float bu, float av, float bv) {
    return au * av * g.X2 + (au * bv + bu * av) * g.XY + bu * bv * g.Y2;
}

__device__ __forceinline__ void g_postclip(const Gram& g, float maxn, float& a, float& b) {
    float n = g_norm(g, a, b);
    float s = fminf(1.0f, div_fast(maxn, n));
    a *= s; b *= s;
}

__device__ __forceinline__ void g_msm(const Gram& g, float sc, float r, float& a, float& b) {
    float n = g_norm(g, a, b);
    float z = fminf(sc * n, F_ATANH_MAX);
    float f = tanh_fast(r * atanh_fast(z)) * rcp_fast(sc * n);
    a *= f; b *= f;
}

__device__ __forceinline__ void g_madd(const Gram& g, float c,
                                       float au, float bu, float av, float bv,
                                       float& ao, float& bo) {
    float u2 = g_norm2(g, au, bu);
    float v2 = g_norm2(g, av, bv);
    float uv = g_dot(g, au, bu, av, bv);
    float A = 1.0f + 2.0f * c * uv + c * v2;
    float B = 1.0f - c * u2;
    float rden = rcp_fast(fmaxf(1.0f + 2.0f * c * uv + c * c * u2 * v2, F_EPS));
    ao = (A * au + B * av) * rden;
    bo = (A * bu + B * bv) * rden;
}

__device__ __forceinline__ float hr_coeff(float n, float sc, float maxn_pre, float maxn_post) {
    float s1 = fminf(1.0f, div_fast(maxn_pre, n));     // pre_clip
    float n1 = fmaxf(s1 * n, F_EPS);
    float f1 = tanh_fast(sc * n1) * rcp_fast(sc * n1); // expmap0
    float a  = s1 * f1;
    float n2 = fmaxf(fabsf(a) * n, F_EPS);
    float s2 = fminf(1.0f, div_fast(maxn_post, n2));   // post_clip
    return a * s2;
}

// Full per-row scalar chain: Gram -> (fa, fb) with out_row = fa*x + fb*y.
__device__ __forceinline__ void row_chain(const Gram& g,
                                          float c, float sc, float maxn_pre, float maxn_post,
                                          float s, float gamma,
                                          float& fa, float& fb) {
    const float nx = fmaxf(sqrt_fast(g.X2), F_EPS);
    const float ny = fmaxf(sqrt_fast(g.Y2), F_EPS);

    const float hx = hr_coeff(nx, sc, maxn_pre, maxn_post);  // hr_x = hx * x
    const float hy = hr_coeff(ny, sc, maxn_pre, maxn_post);  // hr_y = hy * y

    float sxa = hx, sxb = 0.0f;                 // sx = post_clip(msm(s, hr_x))
    g_msm(g, sc, s, sxa, sxb);
    g_postclip(g, maxn_post, sxa, sxb);

    float sya = 0.0f, syb = hy;                 // sy = post_clip(msm(1-s, hr_y))
    g_msm(g, sc, 1.0f - s, sya, syb);
    g_postclip(g, maxn_post, sya, syb);

    float pa, pb;                               // p = post_clip(madd(sx, sy))
    g_madd(g, c, sxa, sxb, sya, syb, pa, pb);
    g_postclip(g, maxn_post, pa, pb);

    float xpa, xpb;                             // x_p = post_clip(madd(-p, hr_x))
    g_madd(g, c, -pa, -pb, hx, 0.0f, xpa, xpb);
    g_postclip(g, maxn_post, xpa, xpb);

    float ypa, ypb;                             // y_p = post_clip(madd(-p, hr_y))
    g_madd(g, c, -pa, -pb, 0.0f, hy, ypa, ypb);
    g_postclip(g, maxn_post, ypa, ypb);

    g_msm(g, sc, gamma, ypa, ypb);              // y_s = post_clip(msm(gamma, y_p))
    g_postclip(g, maxn_post, ypa, ypb);

    float ha, hb;                               // hres_p = post_clip(madd(x_p, y_s))
    g_madd(g, c, xpa, xpb, ypa, ypb, ha, hb);
    g_postclip(g, maxn_post, ha, hb);

    float ra, rb;                               // r = post_clip(madd(p, hres_p))
    g_madd(g, c, pa, pb, ha, hb, ra, rb);
    g_postclip(g, maxn_post, ra, rb);

    float nr = g_norm(g, ra, rb);               // logmap0
    float z  = fminf(sc * nr, F_ATANH_MAX);
    float f  = atanh_fast(z) * rcp_fast(sc * nr);

    fa = f * ra;
    fb = f * rb;
}

// 4 rows per wave; the 4 rows' scalar chains run lane-parallel (lane L handles
// row L&3), results broadcast back via shfl. Data stays in registers.
__global__ __launch_bounds__(256, 3) void hra_kernel(
    const float* __restrict__ x, const float* __restrict__ y,
    const float* __restrict__ p_curv, const float* __restrict__ p_graw,
    const float* __restrict__ p_gscale, const float* __restrict__ p_scent,
    float* __restrict__ out, int rows)
{
    const int wave = (blockIdx.x << 2) | (threadIdx.x >> 6);
    const int lane = threadIdx.x & 63;
    const int base = wave << 2;                  // first of this wave's 4 rows
    if (base >= rows) return;

    // ---- load 4 rows of x and y (3 float4 per row per lane, coalesced) ----
    float4 xv[4][3], yv[4][3];
#pragma unroll
    for (int r = 0; r < 4; r++) {
        const float4* xr = (const float4*)(x) + (size_t)(base + r) * 192;
        const float4* yr = (const float4*)(y) + (size_t)(base + r) * 192;
#pragma unroll
        for (int j = 0; j < 3; j++) {
            xv[r][j] = xr[lane + 64 * j];
            yv[r][j] = yr[lane + 64 * j];
        }
    }

    // ---- per-row Gram partials (12 values/lane) ----
    float sxx[4], syy[4], sxy[4];
#pragma unroll
    for (int r = 0; r < 4; r++) {
        float a = 0.0f, b = 0.0f, d = 0.0f;
#pragma unroll
        for (int j = 0; j < 3; j++) {
            a += xv[r][j].x * xv[r][j].x + xv[r][j].y * xv[r][j].y + xv[r][j].z * xv[r][j].z + xv[r][j].w * xv[r][j].w;
            b += yv[r][j].x * yv[r][j].x + yv[r][j].y * yv[r][j].y + yv[r][j].z * yv[r][j].z + yv[r][j].w * yv[r][j].w;
            d += xv[r][j].x * yv[r][j].x + xv[r][j].y * yv[r][j].y + xv[r][j].z * yv[r][j].z + xv[r][j].w * yv[r][j].w;
        }
        sxx[r] = a; syy[r] = b; sxy[r] = d;
    }

    // ---- butterfly-reduce all 12 values across the wave ----
#pragma unroll
    for (int o = 32; o > 0; o >>= 1) {
#pragma unroll
        for (int r = 0; r < 4; r++) {
            sxx[r] += __shfl_xor(sxx[r], o, 64);
            syy[r] += __shfl_xor(syy[r], o, 64);
            sxy[r] += __shfl_xor(sxy[r], o, 64);
        }
    }

    // ---- lane L takes row (L&3)'s Gram ----
    const int rsel = lane & 3;
    Gram g;
    g.X2 = (rsel < 2) ? (rsel == 0 ? sxx[0] : sxx[1]) : (rsel == 2 ? sxx[2] : sxx[3]);
    g.Y2 = (rsel < 2) ? (rsel == 0 ? syy[0] : syy[1]) : (rsel == 2 ? syy[2] : syy[3]);
    g.XY = (rsel < 2) ? (rsel == 0 ? sxy[0] : sxy[1]) : (rsel == 2 ? sxy[2] : sxy[3]);

    // ---- wave-uniform scalar parameters ----
    const float c  = softplus_fast(p_curv[0]);
    const float sc = sqrt_fast(c);
    const float maxn_pre  = div_fast(F_TANH_ARG_MAX, sc);
    const float maxn_post = div_fast(1.0f - F_BALL_EPS, sc);
    const float s     = rcp_fast(1.0f + exp_fast(-p_scent[0]));  // sigmoid
    const float g_max = 1.0f + softplus_fast(p_gscale[0]);
    const float gamma = g_max * tanh_fast(p_graw[0]);

    // ---- the chain runs ONCE per wave, lane-parallel over the 4 rows ----
    float fa, fb;
    row_chain(g, c, sc, maxn_pre, maxn_post, s, gamma, fa, fb);

    // ---- broadcast row coefficients (uniform-index shfl -> readlane) ----
    float far[4], fbr[4];
#pragma unroll
    for (int r = 0; r < 4; r++) {
        far[r] = __shfl(fa, r, 64);
        fbr[r] = __shfl(fb, r, 64);
    }

    // ---- epilogue: out = fa*x + fb*y, from registers ----
#pragma unroll
    for (int r = 0; r < 4; r++) {
        float4* outr = (float4*)(out) + (size_t)(base + r) * 192;
#pragma unroll
        for (int j = 0; j < 3; j++) {
            float4 o;
            o.x = far[r] * xv[r][j].x + fbr[r] * yv[r][j].x;
            o.y = far[r] * xv[r][j].y + fbr[r] * yv[r][j].y;
            o.z = far[r] * xv[r][j].z + fbr[r] * yv[r][j].z;
            o.w = far[r] * xv[r][j].w + fbr[r] * yv[r][j].w;
            outr[lane + 64 * j] = o;
        }
    }
}

extern "C" void kernel_launch(void* const* d_in, const int* in_sizes, int n_in,
                              void* d_out, int out_size, void* d_ws, size_t ws_size,
                              hipStream_t stream) {
    const float* x = (const float*)d_in[0];
    const float* y = (const float*)d_in[1];
    const float* curv = (const float*)d_in[2];
    const float* graw = (const float*)d_in[3];
    const float* gscale = (const float*)d_in[4];
    const float* scent = (const float*)d_in[5];
    float* out = (float*)d_out;

    const int rows = in_sizes[0] / 768;          // 64*577 = 36928 (divisible by 4)
    const int waves = (rows + 3) / 4;            // 4 rows per wave
    const int blocks = (waves + 3) / 4;          // 4 waves per 256-thread block

    hipLaunchKernelGGL(hra_kernel, dim3(blocks), dim3(256), 0, stream,
                       x, y, curv, graw, gscale, scent, out, rows);
}